// Round 1
// baseline (2044.188 us; speedup 1.0000x reference)
//
#include <hip/hip_runtime.h>

// Problem dims (fixed by the reference)
#define B_DIM 8192
#define N_DIM 1024
#define M_DIM 4096
#define A_DIM 1024
#define LN_EPS 1e-5f

// ---------------------------------------------------------------- copy x -> out
__global__ __launch_bounds__(256) void copy4_kernel(const float4* __restrict__ s,
                                                    float4* __restrict__ d, int n4) {
  int i = blockIdx.x * 256 + threadIdx.x;
  if (i < n4) d[i] = s[i];
}

// ------------------------------------------------- block-wide reduce of 2 floats
// 256 threads = 4 waves of 64. Leading barrier protects smem reuse across calls.
__device__ __forceinline__ void block_reduce2(float& a, float& b, float* sm) {
#pragma unroll
  for (int off = 32; off > 0; off >>= 1) {
    a += __shfl_down(a, off, 64);
    b += __shfl_down(b, off, 64);
  }
  const int lane = threadIdx.x & 63;
  const int wid = threadIdx.x >> 6;
  __syncthreads();
  if (lane == 0) { sm[wid * 2] = a; sm[wid * 2 + 1] = b; }
  __syncthreads();
  a = sm[0] + sm[2] + sm[4] + sm[6];
  b = sm[1] + sm[3] + sm[5] + sm[7];
}

// ---------------------------------------- relu (+optional bias) + LayerNorm, C=1024
// one block (256 thr) per row; 4 elems/thread via float4
__global__ __launch_bounds__(256) void relu_ln_kernel(const float* __restrict__ in,
                                                      const float* __restrict__ bias,
                                                      const float* __restrict__ g,
                                                      const float* __restrict__ bt,
                                                      float* __restrict__ out) {
  __shared__ float sm[8];
  const int row = blockIdx.x;
  const int t = threadIdx.x;
  const float* pin = in + (size_t)row * 1024;
  float* pout = out + (size_t)row * 1024;

  float4 v = *(const float4*)(pin + t * 4);
  if (bias != nullptr) {
    float4 bb = *(const float4*)(bias + t * 4);
    v.x += bb.x; v.y += bb.y; v.z += bb.z; v.w += bb.w;
  }
  v.x = fmaxf(v.x, 0.f); v.y = fmaxf(v.y, 0.f);
  v.z = fmaxf(v.z, 0.f); v.w = fmaxf(v.w, 0.f);

  float s = v.x + v.y + v.z + v.w;
  float ss = v.x * v.x + v.y * v.y + v.z * v.z + v.w * v.w;
  block_reduce2(s, ss, sm);

  const float mean = s * (1.f / 1024.f);
  const float var = ss * (1.f / 1024.f) - mean * mean;  // population var (jnp.var)
  const float rs = rsqrtf(var + LN_EPS);

  const float4 gg = *(const float4*)(g + t * 4);
  const float4 bb = *(const float4*)(bt + t * 4);
  float4 o;
  o.x = (v.x - mean) * rs * gg.x + bb.x;
  o.y = (v.y - mean) * rs * gg.y + bb.y;
  o.z = (v.z - mean) * rs * gg.z + bb.z;
  o.w = (v.w - mean) * rs * gg.w + bb.w;
  *(float4*)(pout + t * 4) = o;
}

// ---------------------------------------------------------------- fp32 GEMM tiles
// C[M_,N_] = A[M_,K] * B[N_,K]^T   (both row-major, shared inner dim K)
// 128x128 tile, BK=16, 256 threads, 8x8 per thread.
#define BM 128
#define BN 128
#define BK 16

__global__ __launch_bounds__(256) void gemm_nt(const float* __restrict__ A,
                                               const float* __restrict__ B,
                                               float* __restrict__ C,
                                               int M_, int N_, int K) {
  __shared__ float As[BK][BM + 4];
  __shared__ float Bs[BK][BN + 4];
  const int t = threadIdx.x;
  const int tx = t & 15;   // col group 0..15
  const int ty = t >> 4;   // row group 0..15
  const int m0 = blockIdx.y * BM;
  const int n0 = blockIdx.x * BN;

  float acc[8][8];
#pragma unroll
  for (int i = 0; i < 8; i++)
#pragma unroll
    for (int j = 0; j < 8; j++) acc[i][j] = 0.f;

  for (int k0 = 0; k0 < K; k0 += BK) {
    // stage A tile: 128 rows x 16 k = 512 float4, 2 per thread
#pragma unroll
    for (int i = 0; i < 2; i++) {
      const int f = t + i * 256;
      const int row = f >> 2;
      const int kq = f & 3;
      const float4 v = *(const float4*)(A + (size_t)(m0 + row) * K + k0 + kq * 4);
      As[kq * 4 + 0][row] = v.x;
      As[kq * 4 + 1][row] = v.y;
      As[kq * 4 + 2][row] = v.z;
      As[kq * 4 + 3][row] = v.w;
    }
    // stage B tile (rows of B, transposed layout in LDS)
#pragma unroll
    for (int i = 0; i < 2; i++) {
      const int f = t + i * 256;
      const int row = f >> 2;
      const int kq = f & 3;
      const float4 v = *(const float4*)(B + (size_t)(n0 + row) * K + k0 + kq * 4);
      Bs[kq * 4 + 0][row] = v.x;
      Bs[kq * 4 + 1][row] = v.y;
      Bs[kq * 4 + 2][row] = v.z;
      Bs[kq * 4 + 3][row] = v.w;
    }
    __syncthreads();
#pragma unroll
    for (int k = 0; k < BK; k++) {
      const float4 a0 = *(const float4*)&As[k][ty * 8];
      const float4 a1 = *(const float4*)&As[k][ty * 8 + 4];
      const float4 b0 = *(const float4*)&Bs[k][tx * 8];
      const float4 b1 = *(const float4*)&Bs[k][tx * 8 + 4];
      const float a[8] = {a0.x, a0.y, a0.z, a0.w, a1.x, a1.y, a1.z, a1.w};
      const float b[8] = {b0.x, b0.y, b0.z, b0.w, b1.x, b1.y, b1.z, b1.w};
#pragma unroll
      for (int i = 0; i < 8; i++)
#pragma unroll
        for (int j = 0; j < 8; j++) acc[i][j] += a[i] * b[j];
    }
    __syncthreads();
  }
#pragma unroll
  for (int i = 0; i < 8; i++) {
    float* cp = C + (size_t)(m0 + ty * 8 + i) * N_ + n0 + tx * 8;
    *(float4*)cp = make_float4(acc[i][0], acc[i][1], acc[i][2], acc[i][3]);
    *(float4*)(cp + 4) = make_float4(acc[i][4], acc[i][5], acc[i][6], acc[i][7]);
  }
}

// C[M_,N_] = A[M_,K] * B[K,N_]   (row-major)
__global__ __launch_bounds__(256) void gemm_nn(const float* __restrict__ A,
                                               const float* __restrict__ B,
                                               float* __restrict__ C,
                                               int M_, int N_, int K) {
  __shared__ float As[BK][BM + 4];
  __shared__ float Bs[BK][BN + 4];
  const int t = threadIdx.x;
  const int tx = t & 15;
  const int ty = t >> 4;
  const int m0 = blockIdx.y * BM;
  const int n0 = blockIdx.x * BN;

  float acc[8][8];
#pragma unroll
  for (int i = 0; i < 8; i++)
#pragma unroll
    for (int j = 0; j < 8; j++) acc[i][j] = 0.f;

  for (int k0 = 0; k0 < K; k0 += BK) {
#pragma unroll
    for (int i = 0; i < 2; i++) {
      const int f = t + i * 256;
      const int row = f >> 2;
      const int kq = f & 3;
      const float4 v = *(const float4*)(A + (size_t)(m0 + row) * K + k0 + kq * 4);
      As[kq * 4 + 0][row] = v.x;
      As[kq * 4 + 1][row] = v.y;
      As[kq * 4 + 2][row] = v.z;
      As[kq * 4 + 3][row] = v.w;
    }
    // B tile: 16 k-rows x 128 cols; contiguous float4 stores
#pragma unroll
    for (int i = 0; i < 2; i++) {
      const int f = t + i * 256;
      const int row = f >> 5;   // 0..15
      const int nq = f & 31;    // 0..31
      const float4 v = *(const float4*)(B + (size_t)(k0 + row) * N_ + n0 + nq * 4);
      *(float4*)&Bs[row][nq * 4] = v;
    }
    __syncthreads();
#pragma unroll
    for (int k = 0; k < BK; k++) {
      const float4 a0 = *(const float4*)&As[k][ty * 8];
      const float4 a1 = *(const float4*)&As[k][ty * 8 + 4];
      const float4 b0 = *(const float4*)&Bs[k][tx * 8];
      const float4 b1 = *(const float4*)&Bs[k][tx * 8 + 4];
      const float a[8] = {a0.x, a0.y, a0.z, a0.w, a1.x, a1.y, a1.z, a1.w};
      const float b[8] = {b0.x, b0.y, b0.z, b0.w, b1.x, b1.y, b1.z, b1.w};
#pragma unroll
      for (int i = 0; i < 8; i++)
#pragma unroll
        for (int j = 0; j < 8; j++) acc[i][j] += a[i] * b[j];
    }
    __syncthreads();
  }
#pragma unroll
  for (int i = 0; i < 8; i++) {
    float* cp = C + (size_t)(m0 + ty * 8 + i) * N_ + n0 + tx * 8;
    *(float4*)cp = make_float4(acc[i][0], acc[i][1], acc[i][2], acc[i][3]);
    *(float4*)(cp + 4) = make_float4(acc[i][4], acc[i][5], acc[i][6], acc[i][7]);
  }
}

// ---------------------------------------------------------------- sparsemax rows
// Michelot simplex projection: tau <- (sum_{s>tau} s - 1)/|{s>tau}| until the
// active-set count stabilizes. Exact same tau as the reference sort/cumsum
// construction (sparsemax == Euclidean projection onto the simplex).
// One block (256 thr) per row of 4096; 16 elems/thread in registers.
__global__ __launch_bounds__(256) void sparsemax_kernel(float* __restrict__ sf,
                                                        float scale) {
  __shared__ float sm[8];
  const int row = blockIdx.x;
  float* p = sf + (size_t)row * 4096;
  const int t = threadIdx.x;

  float s[16];
#pragma unroll
  for (int j = 0; j < 16; j++) {
    float v = p[t + j * 256] * scale;
    s[j] = (v < -1e10f) ? 0.f : v;   // faithful to the reference mask
  }

  float tau = -INFINITY;
  int cnt_prev = -1;
  for (int it = 0; it < 64; ++it) {
    float ls = 0.f, lc = 0.f;
#pragma unroll
    for (int j = 0; j < 16; j++) {
      if (s[j] > tau) { ls += s[j]; lc += 1.f; }
    }
    block_reduce2(ls, lc, sm);          // broadcast: all threads get same values
    const float ntau = (ls - 1.0f) / lc;
    const int ic = (int)lc;
    const bool conv = (ic == cnt_prev); // set unchanged -> tau is the fixed point
    tau = ntau;
    cnt_prev = ic;
    if (conv) break;                    // uniform across block
  }

#pragma unroll
  for (int j = 0; j < 16; j++) p[t + j * 256] = fmaxf(s[j] - tau, 0.f);
}

// ================================================================ launch
extern "C" void kernel_launch(void* const* d_in, const int* in_sizes, int n_in,
                              void* d_out, int out_size, void* d_ws, size_t ws_size,
                              hipStream_t stream) {
  const float* x    = (const float*)d_in[0];   // [B, N]
  const float* Wq_w = (const float*)d_in[1];   // [A, N]
  const float* Wq_b = (const float*)d_in[2];   // [A]
  const float* Wk   = (const float*)d_in[3];   // [M, A]
  const float* Wv   = (const float*)d_in[4];   // [M, N]
  const float* gq   = (const float*)d_in[5];
  const float* bq   = (const float*)d_in[6];
  const float* gk   = (const float*)d_in[7];
  const float* bk   = (const float*)d_in[8];
  const float* gv   = (const float*)d_in[9];
  const float* bv   = (const float*)d_in[10];

  float* out = (float*)d_out;
  float* out_x    = out;                                        // B*N
  float* out_xhat = out + (size_t)B_DIM * N_DIM;                // B*N
  float* out_f    = out_xhat + (size_t)B_DIM * N_DIM;           // B*M
  float* out_v    = out_f + (size_t)B_DIM * M_DIM;              // M*N

  float* ws_q = (float*)d_ws;                     // B*A floats (33.5 MB)
  float* ws_k = ws_q + (size_t)B_DIM * A_DIM;     // M*A floats (16.8 MB)

  // 1) out_x = x (pass-through output)
  {
    const int n4 = (B_DIM * N_DIM) / 4;
    copy4_kernel<<<(n4 + 255) / 256, 256, 0, stream>>>((const float4*)x,
                                                       (float4*)out_x, n4);
  }
  // 2) k = LN(relu(Wk)) -> ws_k ; v = LN(relu(Wv)) -> out_v
  relu_ln_kernel<<<M_DIM, 256, 0, stream>>>(Wk, nullptr, gk, bk, ws_k);
  relu_ln_kernel<<<M_DIM, 256, 0, stream>>>(Wv, nullptr, gv, bv, out_v);

  // 3) q_pre = x @ Wq_w^T  -> ws_q   [B, A]
  gemm_nt<<<dim3(A_DIM / BN, B_DIM / BM), 256, 0, stream>>>(x, Wq_w, ws_q,
                                                            B_DIM, A_DIM, N_DIM);
  // 4) q = LN(relu(q_pre + Wq_b)) in place
  relu_ln_kernel<<<B_DIM, 256, 0, stream>>>(ws_q, Wq_b, gq, bq, ws_q);

  // 5) scores_raw = q @ k^T -> out_f region   [B, M]
  gemm_nt<<<dim3(M_DIM / BN, B_DIM / BM), 256, 0, stream>>>(ws_q, ws_k, out_f,
                                                            B_DIM, M_DIM, A_DIM);
  // 6) f = sparsemax(scores_raw * 1/sqrt(A)) in place
  sparsemax_kernel<<<B_DIM, 256, 0, stream>>>(out_f, 0.03125f);

  // 7) x_hat = f @ v   [B, N]
  gemm_nn<<<dim3(N_DIM / BN, B_DIM / BM), 256, 0, stream>>>(out_f, out_v, out_xhat,
                                                            B_DIM, N_DIM, M_DIM);
}

// Round 2
// 842.251 us; speedup vs baseline: 2.4271x; 2.4271x over previous
//
#include <hip/hip_runtime.h>

// Problem dims (fixed by the reference)
#define B_DIM 8192
#define N_DIM 1024
#define M_DIM 4096
#define A_DIM 1024
#define LN_EPS 1e-5f

typedef short s8v __attribute__((ext_vector_type(8)));   // 8 bf16 (4 VGPRs)
typedef float f4v __attribute__((ext_vector_type(4)));   // 4 fp32 acc

// bf16 round-to-nearest-even, bit-level (inputs finite)
__device__ __forceinline__ unsigned short f2bf(float f) {
  union { float f; unsigned u; } x; x.f = f;
  unsigned r = x.u + 0x7fffu + ((x.u >> 16) & 1u);
  return (unsigned short)(r >> 16);
}
__device__ __forceinline__ float bf2f(unsigned short h) {
  union { unsigned u; float f; } x; x.u = ((unsigned)h) << 16;
  return x.f;
}

// ---------------------------------------------------------------- copy x -> out
__global__ __launch_bounds__(256) void copy4_kernel(const float4* __restrict__ s,
                                                    float4* __restrict__ d, int n4) {
  int i = blockIdx.x * 256 + threadIdx.x;
  if (i < n4) d[i] = s[i];
}

// ------------------------------------------------- block-wide reduce of 2 floats
__device__ __forceinline__ void block_reduce2(float& a, float& b, float* sm) {
#pragma unroll
  for (int off = 32; off > 0; off >>= 1) {
    a += __shfl_down(a, off, 64);
    b += __shfl_down(b, off, 64);
  }
  const int lane = threadIdx.x & 63;
  const int wid = threadIdx.x >> 6;
  __syncthreads();
  if (lane == 0) { sm[wid * 2] = a; sm[wid * 2 + 1] = b; }
  __syncthreads();
  a = sm[0] + sm[2] + sm[4] + sm[6];
  b = sm[1] + sm[3] + sm[5] + sm[7];
}

// ---------------------------------------- relu (+optional bias) + LayerNorm, C=1024
__global__ __launch_bounds__(256) void relu_ln_kernel(const float* __restrict__ in,
                                                      const float* __restrict__ bias,
                                                      const float* __restrict__ g,
                                                      const float* __restrict__ bt,
                                                      float* __restrict__ out) {
  __shared__ float sm[8];
  const int row = blockIdx.x;
  const int t = threadIdx.x;
  const float* pin = in + (size_t)row * 1024;
  float* pout = out + (size_t)row * 1024;

  float4 v = *(const float4*)(pin + t * 4);
  if (bias != nullptr) {
    float4 bb = *(const float4*)(bias + t * 4);
    v.x += bb.x; v.y += bb.y; v.z += bb.z; v.w += bb.w;
  }
  v.x = fmaxf(v.x, 0.f); v.y = fmaxf(v.y, 0.f);
  v.z = fmaxf(v.z, 0.f); v.w = fmaxf(v.w, 0.f);

  float s = v.x + v.y + v.z + v.w;
  float ss = v.x * v.x + v.y * v.y + v.z * v.z + v.w * v.w;
  block_reduce2(s, ss, sm);

  const float mean = s * (1.f / 1024.f);
  const float var = ss * (1.f / 1024.f) - mean * mean;
  const float rs = rsqrtf(var + LN_EPS);

  const float4 gg = *(const float4*)(g + t * 4);
  const float4 bb = *(const float4*)(bt + t * 4);
  float4 o;
  o.x = (v.x - mean) * rs * gg.x + bb.x;
  o.y = (v.y - mean) * rs * gg.y + bb.y;
  o.z = (v.z - mean) * rs * gg.z + bb.z;
  o.w = (v.w - mean) * rs * gg.w + bb.w;
  *(float4*)(pout + t * 4) = o;
}

// ---------------------------------------------------------------- fp32 transpose
// v[4096][1024] -> vt[1024][4096]
__global__ __launch_bounds__(256) void transpose_kernel(const float* __restrict__ v,
                                                        float* __restrict__ vt) {
  __shared__ float tile[32][33];
  const int t = threadIdx.x;
  const int tx = t & 31;
  const int ty = t >> 5;  // 0..7
  const int col0 = blockIdx.x * 32;  // over 1024
  const int row0 = blockIdx.y * 32;  // over 4096
#pragma unroll
  for (int r = 0; r < 4; r++)
    tile[ty + r * 8][tx] = v[(size_t)(row0 + ty + r * 8) * 1024 + col0 + tx];
  __syncthreads();
#pragma unroll
  for (int r = 0; r < 4; r++)
    vt[(size_t)(col0 + ty + r * 8) * 4096 + row0 + tx] = tile[tx][ty + r * 8];
}

// ------------------------------------------------- split-bf16 MFMA GEMM (nt)
// C[M_,N_] = A[M_,K] * B[N_,K]^T, fp32 in/out, internally bf16 hi/lo.
// NSPLIT=3: hi*hi + hi*lo + lo*hi (~fp32 accuracy). NSPLIT=1: hi*hi only.
// 128x128 tile, BK=32, 256 thr = 4 waves, each wave 64x64 via 4x4 MFMA 16x16x32.
#define BKP 40  // 32 + 8 bf16 pad

template <int NSPLIT>
__global__ __launch_bounds__(256) void gemm_split(const float* __restrict__ A,
                                                  const float* __restrict__ B,
                                                  float* __restrict__ C,
                                                  int M_, int N_, int K,
                                                  int lda, int ldb) {
  __shared__ unsigned short Ah[128 * BKP];
  __shared__ unsigned short Bh[128 * BKP];
  __shared__ unsigned short Al[(NSPLIT == 3) ? 128 * BKP : 1];
  __shared__ unsigned short Bl[(NSPLIT == 3) ? 128 * BKP : 1];

  const int t = threadIdx.x;
  const int lane = t & 63;
  const int wv = t >> 6;             // wave 0..3
  const int wm = (wv & 1) * 64;
  const int wn = (wv >> 1) * 64;
  const int fr = lane & 15;          // fragment row
  const int fco = (lane >> 4) * 8;   // fragment k offset
  const int m0 = blockIdx.y * 128;
  const int n0 = blockIdx.x * 128;

  f4v acc[4][4];
#pragma unroll
  for (int i = 0; i < 4; i++)
#pragma unroll
    for (int j = 0; j < 4; j++) acc[i][j] = (f4v)(0.f);

  for (int k0 = 0; k0 < K; k0 += 32) {
    // stage A and B tiles: 128 rows x 32 k each = 1024 float4 per matrix
#pragma unroll
    for (int it = 0; it < 4; it++) {
      const int idx = t + it * 256;
      const int row = idx >> 3;
      const int seg = idx & 7;
      const float4 v = *(const float4*)(A + (size_t)(m0 + row) * lda + k0 + seg * 4);
      ushort4 h;
      h.x = f2bf(v.x); h.y = f2bf(v.y); h.z = f2bf(v.z); h.w = f2bf(v.w);
      *(ushort4*)&Ah[row * BKP + seg * 4] = h;
      if (NSPLIT == 3) {
        ushort4 l;
        l.x = f2bf(v.x - bf2f(h.x)); l.y = f2bf(v.y - bf2f(h.y));
        l.z = f2bf(v.z - bf2f(h.z)); l.w = f2bf(v.w - bf2f(h.w));
        *(ushort4*)&Al[row * BKP + seg * 4] = l;
      }
    }
#pragma unroll
    for (int it = 0; it < 4; it++) {
      const int idx = t + it * 256;
      const int row = idx >> 3;
      const int seg = idx & 7;
      const float4 v = *(const float4*)(B + (size_t)(n0 + row) * ldb + k0 + seg * 4);
      ushort4 h;
      h.x = f2bf(v.x); h.y = f2bf(v.y); h.z = f2bf(v.z); h.w = f2bf(v.w);
      *(ushort4*)&Bh[row * BKP + seg * 4] = h;
      if (NSPLIT == 3) {
        ushort4 l;
        l.x = f2bf(v.x - bf2f(h.x)); l.y = f2bf(v.y - bf2f(h.y));
        l.z = f2bf(v.z - bf2f(h.z)); l.w = f2bf(v.w - bf2f(h.w));
        *(ushort4*)&Bl[row * BKP + seg * 4] = l;
      }
    }
    __syncthreads();

    s8v ah[4], bh[4], al[4], bl[4];
#pragma unroll
    for (int i = 0; i < 4; i++) {
      ah[i] = *(const s8v*)&Ah[(wm + i * 16 + fr) * BKP + fco];
      bh[i] = *(const s8v*)&Bh[(wn + i * 16 + fr) * BKP + fco];
      if (NSPLIT == 3) {
        al[i] = *(const s8v*)&Al[(wm + i * 16 + fr) * BKP + fco];
        bl[i] = *(const s8v*)&Bl[(wn + i * 16 + fr) * BKP + fco];
      }
    }
#pragma unroll
    for (int i = 0; i < 4; i++)
#pragma unroll
      for (int j = 0; j < 4; j++) {
        acc[i][j] = __builtin_amdgcn_mfma_f32_16x16x32_bf16(ah[i], bh[j], acc[i][j], 0, 0, 0);
        if (NSPLIT == 3) {
          acc[i][j] = __builtin_amdgcn_mfma_f32_16x16x32_bf16(ah[i], bl[j], acc[i][j], 0, 0, 0);
          acc[i][j] = __builtin_amdgcn_mfma_f32_16x16x32_bf16(al[i], bh[j], acc[i][j], 0, 0, 0);
        }
      }
    __syncthreads();
  }

  // epilogue: C/D layout for 16x16x32: col = lane&15, row = (lane>>4)*4 + reg
  const int cr = (lane >> 4) * 4;
  const int cc = lane & 15;
#pragma unroll
  for (int i = 0; i < 4; i++)
#pragma unroll
    for (int r = 0; r < 4; r++) {
      float* cp = C + (size_t)(m0 + wm + i * 16 + cr + r) * N_ + n0 + wn + cc;
#pragma unroll
      for (int j = 0; j < 4; j++) cp[j * 16] = acc[i][j][r];
    }
}

// ---------------------------------------------------------------- sparsemax rows
__global__ __launch_bounds__(256) void sparsemax_kernel(float* __restrict__ sf,
                                                        float scale) {
  __shared__ float sm[8];
  const int row = blockIdx.x;
  float* p = sf + (size_t)row * 4096;
  const int t = threadIdx.x;

  float s[16];
#pragma unroll
  for (int j = 0; j < 16; j++) {
    float v = p[t + j * 256] * scale;
    s[j] = (v < -1e10f) ? 0.f : v;
  }

  float tau = -INFINITY;
  int cnt_prev = -1;
  for (int it = 0; it < 64; ++it) {
    float ls = 0.f, lc = 0.f;
#pragma unroll
    for (int j = 0; j < 16; j++) {
      if (s[j] > tau) { ls += s[j]; lc += 1.f; }
    }
    block_reduce2(ls, lc, sm);
    const float ntau = (ls - 1.0f) / lc;
    const int ic = (int)lc;
    const bool conv = (ic == cnt_prev);
    tau = ntau;
    cnt_prev = ic;
    if (conv) break;
  }

#pragma unroll
  for (int j = 0; j < 16; j++) p[t + j * 256] = fmaxf(s[j] - tau, 0.f);
}

// ================================================================ launch
extern "C" void kernel_launch(void* const* d_in, const int* in_sizes, int n_in,
                              void* d_out, int out_size, void* d_ws, size_t ws_size,
                              hipStream_t stream) {
  const float* x    = (const float*)d_in[0];   // [B, N]
  const float* Wq_w = (const float*)d_in[1];   // [A, N]
  const float* Wq_b = (const float*)d_in[2];   // [A]
  const float* Wk   = (const float*)d_in[3];   // [M, A]
  const float* Wv   = (const float*)d_in[4];   // [M, N]
  const float* gq   = (const float*)d_in[5];
  const float* bq   = (const float*)d_in[6];
  const float* gk   = (const float*)d_in[7];
  const float* bk   = (const float*)d_in[8];
  const float* gv   = (const float*)d_in[9];
  const float* bv   = (const float*)d_in[10];

  float* out = (float*)d_out;
  float* out_x    = out;                                  // B*N
  float* out_xhat = out + (size_t)B_DIM * N_DIM;          // B*N
  float* out_f    = out_xhat + (size_t)B_DIM * N_DIM;     // B*M
  float* out_v    = out_f + (size_t)B_DIM * M_DIM;        // M*N

  float* ws_q = (float*)d_ws;                     // B*A floats
  float* ws_k = ws_q + (size_t)B_DIM * A_DIM;     // M*A floats (later reused as vT)

  // 1) out_x = x
  {
    const int n4 = (B_DIM * N_DIM) / 4;
    copy4_kernel<<<(n4 + 255) / 256, 256, 0, stream>>>((const float4*)x,
                                                       (float4*)out_x, n4);
  }
  // 2) k = LN(relu(Wk)) -> ws_k ; v = LN(relu(Wv)) -> out_v
  relu_ln_kernel<<<M_DIM, 256, 0, stream>>>(Wk, nullptr, gk, bk, ws_k);
  relu_ln_kernel<<<M_DIM, 256, 0, stream>>>(Wv, nullptr, gv, bv, out_v);

  // 3) q_pre = x @ Wq_w^T -> ws_q  (split3 for accuracy; feeds scores)
  gemm_split<3><<<dim3(A_DIM / 128, B_DIM / 128), 256, 0, stream>>>(
      x, Wq_w, ws_q, B_DIM, A_DIM, N_DIM, N_DIM, N_DIM);
  // 4) q = LN(relu(q_pre + Wq_b)) in place
  relu_ln_kernel<<<B_DIM, 256, 0, stream>>>(ws_q, Wq_b, gq, bq, ws_q);

  // 5) scores_raw = q @ k^T -> out_f  (split3)
  gemm_split<3><<<dim3(M_DIM / 128, B_DIM / 128), 256, 0, stream>>>(
      ws_q, ws_k, out_f, B_DIM, M_DIM, A_DIM, A_DIM, A_DIM);
  // 6) f = sparsemax(scores * 1/sqrt(A)) in place
  sparsemax_kernel<<<B_DIM, 256, 0, stream>>>(out_f, 0.03125f);

  // 7) vT = out_v^T -> ws_k region (k no longer needed); [1024][4096]
  transpose_kernel<<<dim3(N_DIM / 32, M_DIM / 32), 256, 0, stream>>>(out_v, ws_k);

  // 8) x_hat = f @ vT^T  (single bf16 pass; 0.4% rel << 2% threshold)
  gemm_split<1><<<dim3(N_DIM / 128, B_DIM / 128), 256, 0, stream>>>(
      out_f, ws_k, out_xhat, B_DIM, N_DIM, M_DIM, M_DIM, M_DIM);
}

// Round 3
// 765.901 us; speedup vs baseline: 2.6690x; 1.0997x over previous
//
#include <hip/hip_runtime.h>

// Problem dims (fixed by the reference)
#define B_DIM 8192
#define N_DIM 1024
#define M_DIM 4096
#define A_DIM 1024
#define LN_EPS 1e-5f

typedef short s8v __attribute__((ext_vector_type(8)));   // 8 bf16 (4 VGPRs)
typedef float f4v __attribute__((ext_vector_type(4)));   // 4 fp32 acc
typedef unsigned short u16;

// bf16 round-to-nearest-even, bit-level (inputs finite)
__device__ __forceinline__ u16 f2bf(float f) {
  union { float f; unsigned u; } x; x.f = f;
  unsigned r = x.u + 0x7fffu + ((x.u >> 16) & 1u);
  return (u16)(r >> 16);
}
__device__ __forceinline__ float bf2f(u16 h) {
  union { unsigned u; float f; } x; x.u = ((unsigned)h) << 16;
  return x.f;
}

// async global->LDS, 16 B per lane. LDS dest = wave-uniform base + lane*16.
__device__ __forceinline__ void glds16(const void* g, void* l) {
  __builtin_amdgcn_global_load_lds(
      (const __attribute__((address_space(1))) unsigned int*)g,
      (__attribute__((address_space(3))) unsigned int*)l, 16, 0, 0);
}

// ---------------------------------------------------------------- copy x -> out
__global__ __launch_bounds__(256) void copy4_kernel(const float4* __restrict__ s,
                                                    float4* __restrict__ d, int n4) {
  int i = blockIdx.x * 256 + threadIdx.x;
  if (i < n4) d[i] = s[i];
}

// -------------------------------------------------- fp32 -> bf16 hi/lo planes
__global__ __launch_bounds__(256) void split_convert_kernel(const float* __restrict__ in,
                                                            u16* __restrict__ hi,
                                                            u16* __restrict__ lo, int n8) {
  int i = blockIdx.x * 256 + threadIdx.x;
  if (i >= n8) return;
  const float* src = in + (size_t)i * 8;
  float4 v0 = *(const float4*)src;
  float4 v1 = *(const float4*)(src + 4);
  const float f[8] = {v0.x, v0.y, v0.z, v0.w, v1.x, v1.y, v1.z, v1.w};
  s8v h, l;
#pragma unroll
  for (int j = 0; j < 8; j++) {
    u16 hh = f2bf(f[j]);
    h[j] = (short)hh;
    l[j] = (short)f2bf(f[j] - bf2f(hh));
  }
  *(s8v*)(hi + (size_t)i * 8) = h;
  *(s8v*)(lo + (size_t)i * 8) = l;
}

// ------------------------------------------------- block-wide reduce of 2 floats
__device__ __forceinline__ void block_reduce2(float& a, float& b, float* sm) {
#pragma unroll
  for (int off = 32; off > 0; off >>= 1) {
    a += __shfl_down(a, off, 64);
    b += __shfl_down(b, off, 64);
  }
  const int lane = threadIdx.x & 63;
  const int wid = threadIdx.x >> 6;
  __syncthreads();
  if (lane == 0) { sm[wid * 2] = a; sm[wid * 2 + 1] = b; }
  __syncthreads();
  a = sm[0] + sm[2] + sm[4] + sm[6];
  b = sm[1] + sm[3] + sm[5] + sm[7];
}

// ------------------------- relu(+bias) + LayerNorm, C=1024; fp32 and/or bf16 out
__global__ __launch_bounds__(256) void relu_ln_kernel(const float* __restrict__ in,
                                                      const float* __restrict__ bias,
                                                      const float* __restrict__ g,
                                                      const float* __restrict__ bt,
                                                      float* __restrict__ outf,
                                                      u16* __restrict__ outh,
                                                      u16* __restrict__ outl) {
  __shared__ float sm[8];
  const int row = blockIdx.x;
  const int t = threadIdx.x;
  const float* pin = in + (size_t)row * 1024;

  float4 v = *(const float4*)(pin + t * 4);
  if (bias != nullptr) {
    float4 bb = *(const float4*)(bias + t * 4);
    v.x += bb.x; v.y += bb.y; v.z += bb.z; v.w += bb.w;
  }
  v.x = fmaxf(v.x, 0.f); v.y = fmaxf(v.y, 0.f);
  v.z = fmaxf(v.z, 0.f); v.w = fmaxf(v.w, 0.f);

  float s = v.x + v.y + v.z + v.w;
  float ss = v.x * v.x + v.y * v.y + v.z * v.z + v.w * v.w;
  block_reduce2(s, ss, sm);

  const float mean = s * (1.f / 1024.f);
  const float var = ss * (1.f / 1024.f) - mean * mean;
  const float rs = rsqrtf(var + LN_EPS);

  const float4 gg = *(const float4*)(g + t * 4);
  const float4 bb = *(const float4*)(bt + t * 4);
  float o[4];
  o[0] = (v.x - mean) * rs * gg.x + bb.x;
  o[1] = (v.y - mean) * rs * gg.y + bb.y;
  o[2] = (v.z - mean) * rs * gg.z + bb.z;
  o[3] = (v.w - mean) * rs * gg.w + bb.w;

  if (outf != nullptr)
    *(float4*)(outf + (size_t)row * 1024 + t * 4) = make_float4(o[0], o[1], o[2], o[3]);
  if (outh != nullptr) {
    ushort4 h, l;
    h.x = f2bf(o[0]); h.y = f2bf(o[1]); h.z = f2bf(o[2]); h.w = f2bf(o[3]);
    l.x = f2bf(o[0] - bf2f(h.x)); l.y = f2bf(o[1] - bf2f(h.y));
    l.z = f2bf(o[2] - bf2f(h.z)); l.w = f2bf(o[3] - bf2f(h.w));
    *(ushort4*)(outh + (size_t)row * 1024 + t * 4) = h;
    *(ushort4*)(outl + (size_t)row * 1024 + t * 4) = l;
  }
}

// ------------------------------------------- fp32 v -> bf16 v^T  [1024][4096]
__global__ __launch_bounds__(256) void transpose_bf16_kernel(const float* __restrict__ v,
                                                             u16* __restrict__ vt) {
  __shared__ float tile[32][33];
  const int t = threadIdx.x;
  const int tx = t & 31;
  const int ty = t >> 5;  // 0..7
  const int col0 = blockIdx.x * 32;  // over 1024
  const int row0 = blockIdx.y * 32;  // over 4096
#pragma unroll
  for (int r = 0; r < 4; r++)
    tile[ty + r * 8][tx] = v[(size_t)(row0 + ty + r * 8) * 1024 + col0 + tx];
  __syncthreads();
#pragma unroll
  for (int r = 0; r < 4; r++)
    vt[(size_t)(col0 + ty + r * 8) * 4096 + row0 + tx] = f2bf(tile[tx][ty + r * 8]);
}

// ------------------------------------------------- split-bf16 MFMA GEMM (nt)
// C[M_,N_] = A[M_,K] * B[N_,K]^T. A/B as pre-split bf16 hi/lo planes (A_BF16)
// or A as fp32 converted in staging (!A_BF16, NSPLIT==1).
// 128x128 tile, BK=32, 4 waves, each 64x64 via 4x4 of mfma 16x16x32 bf16.
// LDS rows are 32 bf16 = 4 chunks of 16 B; chunk slot = g ^ ((row>>1)&3)
// (XOR swizzle keeps ds_read_b128 at 2-way bank aliasing = free, and is
// compatible with global_load_lds's lane-contiguous LDS destination).
template <int NSPLIT, bool A_BF16>
__global__ __launch_bounds__(256) void gemm_mfma(const u16* __restrict__ AhG,
                                                 const u16* __restrict__ AlG,
                                                 const float* __restrict__ AfG,
                                                 const u16* __restrict__ BhG,
                                                 const u16* __restrict__ BlG,
                                                 float* __restrict__ C,
                                                 int N_, int K, int lda, int ldb) {
  __shared__ __align__(16) u16 Ah[128 * 32];
  __shared__ __align__(16) u16 Bh[128 * 32];
  __shared__ __align__(16) u16 Al[NSPLIT == 3 ? 128 * 32 : 8];
  __shared__ __align__(16) u16 Bl[NSPLIT == 3 ? 128 * 32 : 8];

  const int t = threadIdx.x;
  const int lane = t & 63;
  const int wv = t >> 6;
  const int wm = (wv & 1) * 64;
  const int wn = (wv >> 1) * 64;
  const int m0 = blockIdx.y * 128;
  const int n0 = blockIdx.x * 128;

  // glds lane geometry: within a 16-row chunk, lane covers row=lane>>2, slot=lane&3
  const int ge = lane >> 2;
  const int gg = (lane & 3) ^ ((ge >> 1) & 3);  // logical k-chunk to fetch

  // fragment geometry: lane reads row (lane&15), logical chunk (lane>>4)
  const int fr = lane & 15;
  const int fslot = (((lane >> 4) ^ ((fr >> 1) & 3))) * 8;

  f4v acc[4][4];
#pragma unroll
  for (int i = 0; i < 4; i++)
#pragma unroll
    for (int j = 0; j < 4; j++) acc[i][j] = (f4v)(0.f);

  for (int k0 = 0; k0 < K; k0 += 32) {
    if (A_BF16) {
#pragma unroll
      for (int h = 0; h < 2; h++) {
        const int c = wv * 2 + h;               // chunk 0..7
        const size_t goff = (size_t)(m0 + c * 16 + ge) * lda + k0 + gg * 8;
        glds16(AhG + goff, &Ah[c * 512]);
        if constexpr (NSPLIT == 3) glds16(AlG + goff, &Al[c * 512]);
      }
    } else {
      // manual fp32 -> bf16 staging (A operand only, split1)
#pragma unroll
      for (int it = 0; it < 2; it++) {
        const int idx = t + it * 256;           // 0..511
        const int row = idx >> 2;
        const int g = idx & 3;
        const float* src = AfG + (size_t)(m0 + row) * lda + k0 + g * 8;
        float4 v0 = *(const float4*)src;
        float4 v1 = *(const float4*)(src + 4);
        const float f[8] = {v0.x, v0.y, v0.z, v0.w, v1.x, v1.y, v1.z, v1.w};
        s8v hv;
#pragma unroll
        for (int j = 0; j < 8; j++) hv[j] = (short)f2bf(f[j]);
        *(s8v*)&Ah[row * 32 + (g ^ ((row >> 1) & 3)) * 8] = hv;
      }
    }
#pragma unroll
    for (int h = 0; h < 2; h++) {
      const int c = wv * 2 + h;
      const size_t goff = (size_t)(n0 + c * 16 + ge) * ldb + k0 + gg * 8;
      glds16(BhG + goff, &Bh[c * 512]);
      if constexpr (NSPLIT == 3) glds16(BlG + goff, &Bl[c * 512]);
    }
    __syncthreads();

    s8v ah[4], bh[4], al[4], bl[4];
#pragma unroll
    for (int i = 0; i < 4; i++) {
      ah[i] = *(const s8v*)&Ah[(wm + i * 16 + fr) * 32 + fslot];
      bh[i] = *(const s8v*)&Bh[(wn + i * 16 + fr) * 32 + fslot];
      if constexpr (NSPLIT == 3) {
        al[i] = *(const s8v*)&Al[(wm + i * 16 + fr) * 32 + fslot];
        bl[i] = *(const s8v*)&Bl[(wn + i * 16 + fr) * 32 + fslot];
      }
    }
#pragma unroll
    for (int i = 0; i < 4; i++)
#pragma unroll
      for (int j = 0; j < 4; j++) {
        acc[i][j] = __builtin_amdgcn_mfma_f32_16x16x32_bf16(ah[i], bh[j], acc[i][j], 0, 0, 0);
        if constexpr (NSPLIT == 3) {
          acc[i][j] = __builtin_amdgcn_mfma_f32_16x16x32_bf16(ah[i], bl[j], acc[i][j], 0, 0, 0);
          acc[i][j] = __builtin_amdgcn_mfma_f32_16x16x32_bf16(al[i], bh[j], acc[i][j], 0, 0, 0);
        }
      }
    __syncthreads();
  }

  // epilogue: C/D layout 16x16x32: col = lane&15, row = (lane>>4)*4 + reg
  const int cr = (lane >> 4) * 4;
  const int cc = lane & 15;
#pragma unroll
  for (int i = 0; i < 4; i++)
#pragma unroll
    for (int r = 0; r < 4; r++) {
      float* cp = C + (size_t)(m0 + wm + i * 16 + cr + r) * N_ + n0 + wn + cc;
#pragma unroll
      for (int j = 0; j < 4; j++) cp[j * 16] = acc[i][j][r];
    }
}

// ---------------------------------------------------------------- sparsemax rows
__global__ __launch_bounds__(256) void sparsemax_kernel(float* __restrict__ sf,
                                                        float scale) {
  __shared__ float sm[8];
  const int row = blockIdx.x;
  float* p = sf + (size_t)row * 4096;
  const int t = threadIdx.x;

  float s[16];
#pragma unroll
  for (int j = 0; j < 16; j++) {
    float v = p[t + j * 256] * scale;
    s[j] = (v < -1e10f) ? 0.f : v;
  }

  float tau = -INFINITY;
  int cnt_prev = -1;
  for (int it = 0; it < 64; ++it) {
    float ls = 0.f, lc = 0.f;
#pragma unroll
    for (int j = 0; j < 16; j++) {
      if (s[j] > tau) { ls += s[j]; lc += 1.f; }
    }
    block_reduce2(ls, lc, sm);
    const float ntau = (ls - 1.0f) / lc;
    const int ic = (int)lc;
    const bool conv = (ic == cnt_prev);
    tau = ntau;
    cnt_prev = ic;
    if (conv) break;
  }

#pragma unroll
  for (int j = 0; j < 16; j++) p[t + j * 256] = fmaxf(s[j] - tau, 0.f);
}

// ================================================================ launch
extern "C" void kernel_launch(void* const* d_in, const int* in_sizes, int n_in,
                              void* d_out, int out_size, void* d_ws, size_t ws_size,
                              hipStream_t stream) {
  const float* x    = (const float*)d_in[0];   // [B, N]
  const float* Wq_w = (const float*)d_in[1];   // [A, N]
  const float* Wq_b = (const float*)d_in[2];   // [A]
  const float* Wk   = (const float*)d_in[3];   // [M, A]
  const float* Wv   = (const float*)d_in[4];   // [M, N]
  const float* gq   = (const float*)d_in[5];
  const float* bq   = (const float*)d_in[6];
  const float* gk   = (const float*)d_in[7];
  const float* bk   = (const float*)d_in[8];
  const float* gv   = (const float*)d_in[9];
  const float* bv   = (const float*)d_in[10];

  float* out = (float*)d_out;
  float* out_x    = out;                                  // B*N
  float* out_xhat = out + (size_t)B_DIM * N_DIM;          // B*N
  float* out_f    = out_xhat + (size_t)B_DIM * N_DIM;     // B*M
  float* out_v    = out_f + (size_t)B_DIM * M_DIM;        // M*N

  // ws layout (bf16 planes); x-planes are overwritten by q-planes after qproj.
  u16* wsu = (u16*)d_ws;
  u16* xh = wsu;                                   // [B*N]  (later: qh [B*A])
  u16* xl = xh + (size_t)B_DIM * N_DIM;            // [B*N]  (later: ql)
  u16* wqh = xl + (size_t)B_DIM * N_DIM;           // [A*N]
  u16* wql = wqh + (size_t)A_DIM * N_DIM;          // [A*N]
  u16* kh = wql + (size_t)A_DIM * N_DIM;           // [M*A]
  u16* kl = kh + (size_t)M_DIM * A_DIM;            // [M*A]
  u16* vt = kl + (size_t)M_DIM * A_DIM;            // [N*M] bf16 v^T
  // q_pre fp32 borrows the out_xhat region (free until the last GEMM)
  float* q_pre = out_xhat;

  // 1) out_x = x
  {
    const int n4 = (B_DIM * N_DIM) / 4;
    copy4_kernel<<<(n4 + 255) / 256, 256, 0, stream>>>((const float4*)x,
                                                       (float4*)out_x, n4);
  }
  // 2) pre-split x and Wq to bf16 hi/lo planes
  split_convert_kernel<<<(B_DIM * N_DIM / 8 + 255) / 256, 256, 0, stream>>>(
      x, xh, xl, B_DIM * N_DIM / 8);
  split_convert_kernel<<<(A_DIM * N_DIM / 8 + 255) / 256, 256, 0, stream>>>(
      Wq_w, wqh, wql, A_DIM * N_DIM / 8);
  // 3) k = LN(relu(Wk)) -> bf16 planes ; v = LN(relu(Wv)) -> fp32 out_v
  relu_ln_kernel<<<M_DIM, 256, 0, stream>>>(Wk, nullptr, gk, bk, nullptr, kh, kl);
  relu_ln_kernel<<<M_DIM, 256, 0, stream>>>(Wv, nullptr, gv, bv, out_v, nullptr, nullptr);

  // 4) q_pre = x @ Wq_w^T (split3, bf16 planes)
  gemm_mfma<3, true><<<dim3(A_DIM / 128, B_DIM / 128), 256, 0, stream>>>(
      xh, xl, nullptr, wqh, wql, q_pre, A_DIM, N_DIM, N_DIM, N_DIM);
  // 5) q = LN(relu(q_pre + b)) -> bf16 planes (overwrite x planes)
  relu_ln_kernel<<<B_DIM, 256, 0, stream>>>(q_pre, Wq_b, gq, bq, nullptr, xh, xl);

  // 6) scores = q @ k^T (split3) -> out_f
  gemm_mfma<3, true><<<dim3(M_DIM / 128, B_DIM / 128), 256, 0, stream>>>(
      xh, xl, nullptr, kh, kl, out_f, M_DIM, A_DIM, A_DIM, A_DIM);
  // 7) f = sparsemax(scores / 32) in place
  sparsemax_kernel<<<B_DIM, 256, 0, stream>>>(out_f, 0.03125f);

  // 8) vT bf16
  transpose_bf16_kernel<<<dim3(N_DIM / 32, M_DIM / 32), 256, 0, stream>>>(out_v, vt);

  // 9) x_hat = f @ vT^T (split1; A=f fp32 converted in staging)
  gemm_mfma<1, false><<<dim3(N_DIM / 128, B_DIM / 128), 256, 0, stream>>>(
      nullptr, nullptr, out_f, vt, nullptr, out_xhat, N_DIM, M_DIM, M_DIM, M_DIM);
}

// Round 4
// 733.592 us; speedup vs baseline: 2.7865x; 1.0440x over previous
//
#include <hip/hip_runtime.h>

// Problem dims (fixed by the reference)
#define B_DIM 8192
#define N_DIM 1024
#define M_DIM 4096
#define A_DIM 1024
#define LN_EPS 1e-5f

typedef short s8v __attribute__((ext_vector_type(8)));   // 8 bf16 (4 VGPRs)
typedef float f4v __attribute__((ext_vector_type(4)));   // 4 fp32 acc
typedef unsigned short u16;

// bf16 round-to-nearest-even, bit-level (inputs finite)
__device__ __forceinline__ u16 f2bf(float f) {
  union { float f; unsigned u; } x; x.f = f;
  unsigned r = x.u + 0x7fffu + ((x.u >> 16) & 1u);
  return (u16)(r >> 16);
}
__device__ __forceinline__ float bf2f(u16 h) {
  union { unsigned u; float f; } x; x.u = ((unsigned)h) << 16;
  return x.f;
}

// async global->LDS, 16 B per lane. LDS dest = wave-uniform base + lane*16.
__device__ __forceinline__ void glds16(const void* g, void* l) {
  __builtin_amdgcn_global_load_lds(
      (const __attribute__((address_space(1))) unsigned int*)g,
      (__attribute__((address_space(3))) unsigned int*)l, 16, 0, 0);
}

// ---------------------------------- fused: out_x = x ; x -> bf16 hi/lo planes
__global__ __launch_bounds__(256) void copy_split_kernel(const float* __restrict__ in,
                                                         float* __restrict__ outc,
                                                         u16* __restrict__ hi,
                                                         u16* __restrict__ lo, int n8) {
  int i = blockIdx.x * 256 + threadIdx.x;
  if (i >= n8) return;
  const float* src = in + (size_t)i * 8;
  float4 v0 = *(const float4*)src;
  float4 v1 = *(const float4*)(src + 4);
  *(float4*)(outc + (size_t)i * 8) = v0;
  *(float4*)(outc + (size_t)i * 8 + 4) = v1;
  const float f[8] = {v0.x, v0.y, v0.z, v0.w, v1.x, v1.y, v1.z, v1.w};
  s8v h, l;
#pragma unroll
  for (int j = 0; j < 8; j++) {
    u16 hh = f2bf(f[j]);
    h[j] = (short)hh;
    l[j] = (short)f2bf(f[j] - bf2f(hh));
  }
  *(s8v*)(hi + (size_t)i * 8) = h;
  *(s8v*)(lo + (size_t)i * 8) = l;
}

// -------------------------------------------------- fp32 -> bf16 hi/lo planes
__global__ __launch_bounds__(256) void split_convert_kernel(const float* __restrict__ in,
                                                            u16* __restrict__ hi,
                                                            u16* __restrict__ lo, int n8) {
  int i = blockIdx.x * 256 + threadIdx.x;
  if (i >= n8) return;
  const float* src = in + (size_t)i * 8;
  float4 v0 = *(const float4*)src;
  float4 v1 = *(const float4*)(src + 4);
  const float f[8] = {v0.x, v0.y, v0.z, v0.w, v1.x, v1.y, v1.z, v1.w};
  s8v h, l;
#pragma unroll
  for (int j = 0; j < 8; j++) {
    u16 hh = f2bf(f[j]);
    h[j] = (short)hh;
    l[j] = (short)f2bf(f[j] - bf2f(hh));
  }
  *(s8v*)(hi + (size_t)i * 8) = h;
  *(s8v*)(lo + (size_t)i * 8) = l;
}

// ------------------------------------------------- block-wide reduce of 2 floats
__device__ __forceinline__ void block_reduce2(float& a, float& b, float* sm) {
#pragma unroll
  for (int off = 32; off > 0; off >>= 1) {
    a += __shfl_down(a, off, 64);
    b += __shfl_down(b, off, 64);
  }
  const int lane = threadIdx.x & 63;
  const int wid = threadIdx.x >> 6;
  __syncthreads();
  if (lane == 0) { sm[wid * 2] = a; sm[wid * 2 + 1] = b; }
  __syncthreads();
  a = sm[0] + sm[2] + sm[4] + sm[6];
  b = sm[1] + sm[3] + sm[5] + sm[7];
}

// ------------------------- relu(+bias) + LayerNorm, C=1024; fp32 and/or bf16 out
__global__ __launch_bounds__(256) void relu_ln_kernel(const float* __restrict__ in,
                                                      const float* __restrict__ bias,
                                                      const float* __restrict__ g,
                                                      const float* __restrict__ bt,
                                                      float* __restrict__ outf,
                                                      u16* __restrict__ outh,
                                                      u16* __restrict__ outl) {
  __shared__ float sm[8];
  const int row = blockIdx.x;
  const int t = threadIdx.x;
  const float* pin = in + (size_t)row * 1024;

  float4 v = *(const float4*)(pin + t * 4);
  if (bias != nullptr) {
    float4 bb = *(const float4*)(bias + t * 4);
    v.x += bb.x; v.y += bb.y; v.z += bb.z; v.w += bb.w;
  }
  v.x = fmaxf(v.x, 0.f); v.y = fmaxf(v.y, 0.f);
  v.z = fmaxf(v.z, 0.f); v.w = fmaxf(v.w, 0.f);

  float s = v.x + v.y + v.z + v.w;
  float ss = v.x * v.x + v.y * v.y + v.z * v.z + v.w * v.w;
  block_reduce2(s, ss, sm);

  const float mean = s * (1.f / 1024.f);
  const float var = ss * (1.f / 1024.f) - mean * mean;
  const float rs = rsqrtf(var + LN_EPS);

  const float4 gg = *(const float4*)(g + t * 4);
  const float4 bb = *(const float4*)(bt + t * 4);
  float o[4];
  o[0] = (v.x - mean) * rs * gg.x + bb.x;
  o[1] = (v.y - mean) * rs * gg.y + bb.y;
  o[2] = (v.z - mean) * rs * gg.z + bb.z;
  o[3] = (v.w - mean) * rs * gg.w + bb.w;

  if (outf != nullptr)
    *(float4*)(outf + (size_t)row * 1024 + t * 4) = make_float4(o[0], o[1], o[2], o[3]);
  if (outh != nullptr) {
    ushort4 h, l;
    h.x = f2bf(o[0]); h.y = f2bf(o[1]); h.z = f2bf(o[2]); h.w = f2bf(o[3]);
    l.x = f2bf(o[0] - bf2f(h.x)); l.y = f2bf(o[1] - bf2f(h.y));
    l.z = f2bf(o[2] - bf2f(h.z)); l.w = f2bf(o[3] - bf2f(h.w));
    *(ushort4*)(outh + (size_t)row * 1024 + t * 4) = h;
    *(ushort4*)(outl + (size_t)row * 1024 + t * 4) = l;
  }
}

// ------------------------------------------- fp32 v -> bf16 v^T  [1024][4096]
__global__ __launch_bounds__(256) void transpose_bf16_kernel(const float* __restrict__ v,
                                                             u16* __restrict__ vt) {
  __shared__ float tile[32][33];
  const int t = threadIdx.x;
  const int tx = t & 31;
  const int ty = t >> 5;  // 0..7
  const int col0 = blockIdx.x * 32;  // over 1024
  const int row0 = blockIdx.y * 32;  // over 4096
#pragma unroll
  for (int r = 0; r < 4; r++)
    tile[ty + r * 8][tx] = v[(size_t)(row0 + ty + r * 8) * 1024 + col0 + tx];
  __syncthreads();
#pragma unroll
  for (int r = 0; r < 4; r++)
    vt[(size_t)(col0 + ty + r * 8) * 4096 + row0 + tx] = f2bf(tile[tx][ty + r * 8]);
}

// ------------------------------------------------- split-bf16 MFMA GEMM (nt)
// C[M_,N_] = A[M_,K] * B[N_,K]^T. A/B as pre-split bf16 hi/lo planes (A_BF16)
// or A as fp32 converted in staging (!A_BF16, NSPLIT==1).
// 128x128 tile, BK=32, 4 waves, each 64x64 via 4x4 of mfma 16x16x32 bf16.
// LDS rows are 32 bf16 = 4 chunks of 16 B; chunk c lives at slot c^((row>>1)&3)
// (2-way bank aliasing on ds_read_b128 = free; compatible with glds destination).
template <int NSPLIT, bool A_BF16>
__global__ __launch_bounds__(256) void gemm_mfma(const u16* __restrict__ AhG,
                                                 const u16* __restrict__ AlG,
                                                 const float* __restrict__ AfG,
                                                 const u16* __restrict__ BhG,
                                                 const u16* __restrict__ BlG,
                                                 float* __restrict__ C,
                                                 int N_, int K, int lda, int ldb) {
  __shared__ __align__(16) u16 Ah[128 * 32];
  __shared__ __align__(16) u16 Bh[128 * 32];
  __shared__ __align__(16) u16 Al[NSPLIT == 3 ? 128 * 32 : 8];
  __shared__ __align__(16) u16 Bl[NSPLIT == 3 ? 128 * 32 : 8];

  const int t = threadIdx.x;
  const int lane = t & 63;
  const int wv = t >> 6;
  const int wm = (wv & 1) * 64;
  const int wn = (wv >> 1) * 64;
  const int m0 = blockIdx.y * 128;
  const int n0 = blockIdx.x * 128;

  // glds lane geometry: within a 16-row chunk, lane covers row=lane>>2, slot=lane&3
  const int ge = lane >> 2;
  const int gg = (lane & 3) ^ ((ge >> 1) & 3);  // global k-chunk to fetch

  // fragment geometry: lane reads row (lane&15), logical chunk (lane>>4)
  const int fr = lane & 15;
  const int fslot = (((lane >> 4) ^ ((fr >> 1) & 3))) * 8;

  f4v acc[4][4];
#pragma unroll
  for (int i = 0; i < 4; i++)
#pragma unroll
    for (int j = 0; j < 4; j++) acc[i][j] = (f4v)(0.f);

  for (int k0 = 0; k0 < K; k0 += 32) {
    if (A_BF16) {
#pragma unroll
      for (int h = 0; h < 2; h++) {
        const int c = wv * 2 + h;               // chunk 0..7
        const size_t goff = (size_t)(m0 + c * 16 + ge) * lda + k0 + gg * 8;
        glds16(AhG + goff, &Ah[c * 512]);
        if constexpr (NSPLIT == 3) glds16(AlG + goff, &Al[c * 512]);
      }
    } else {
      // manual fp32 -> bf16 staging (A operand only, split1)
#pragma unroll
      for (int it = 0; it < 2; it++) {
        const int idx = t + it * 256;           // 0..511
        const int row = idx >> 2;
        const int g = idx & 3;
        const float* src = AfG + (size_t)(m0 + row) * lda + k0 + g * 8;
        float4 v0 = *(const float4*)src;
        float4 v1 = *(const float4*)(src + 4);
        const float f[8] = {v0.x, v0.y, v0.z, v0.w, v1.x, v1.y, v1.z, v1.w};
        s8v hv;
#pragma unroll
        for (int j = 0; j < 8; j++) hv[j] = (short)f2bf(f[j]);
        *(s8v*)&Ah[row * 32 + (g ^ ((row >> 1) & 3)) * 8] = hv;
      }
    }
#pragma unroll
    for (int h = 0; h < 2; h++) {
      const int c = wv * 2 + h;
      const size_t goff = (size_t)(n0 + c * 16 + ge) * ldb + k0 + gg * 8;
      glds16(BhG + goff, &Bh[c * 512]);
      if constexpr (NSPLIT == 3) glds16(BlG + goff, &Bl[c * 512]);
    }
    __syncthreads();

    s8v ah[4], bh[4], al[4], bl[4];
#pragma unroll
    for (int i = 0; i < 4; i++) {
      ah[i] = *(const s8v*)&Ah[(wm + i * 16 + fr) * 32 + fslot];
      bh[i] = *(const s8v*)&Bh[(wn + i * 16 + fr) * 32 + fslot];
      if constexpr (NSPLIT == 3) {
        al[i] = *(const s8v*)&Al[(wm + i * 16 + fr) * 32 + fslot];
        bl[i] = *(const s8v*)&Bl[(wn + i * 16 + fr) * 32 + fslot];
      }
    }
#pragma unroll
    for (int i = 0; i < 4; i++)
#pragma unroll
      for (int j = 0; j < 4; j++) {
        acc[i][j] = __builtin_amdgcn_mfma_f32_16x16x32_bf16(ah[i], bh[j], acc[i][j], 0, 0, 0);
        if constexpr (NSPLIT == 3) {
          acc[i][j] = __builtin_amdgcn_mfma_f32_16x16x32_bf16(ah[i], bl[j], acc[i][j], 0, 0, 0);
          acc[i][j] = __builtin_amdgcn_mfma_f32_16x16x32_bf16(al[i], bh[j], acc[i][j], 0, 0, 0);
        }
      }
    __syncthreads();
  }

  // epilogue: C/D layout 16x16x32: col = lane&15, row = (lane>>4)*4 + reg
  const int cr = (lane >> 4) * 4;
  const int cc = lane & 15;
#pragma unroll
  for (int i = 0; i < 4; i++)
#pragma unroll
    for (int r = 0; r < 4; r++) {
      float* cp = C + (size_t)(m0 + wm + i * 16 + cr + r) * N_ + n0 + wn + cc;
#pragma unroll
      for (int j = 0; j < 4; j++) cp[j * 16] = acc[i][j][r];
    }
}

// ---------------------------------------------------------------- sparsemax rows
// Michelot simplex projection (exact sparsemax tau). Optionally also emits the
// bf16 image of f (same values the GEMM staging conversion would compute).
__global__ __launch_bounds__(256) void sparsemax_kernel(float* __restrict__ sf,
                                                        float scale,
                                                        u16* __restrict__ fh) {
  __shared__ float sm[8];
  const int row = blockIdx.x;
  float* p = sf + (size_t)row * 4096;
  const int t = threadIdx.x;

  float s[16];
#pragma unroll
  for (int j = 0; j < 16; j++) {
    float v = p[t + j * 256] * scale;
    s[j] = (v < -1e10f) ? 0.f : v;
  }

  float tau = -INFINITY;
  int cnt_prev = -1;
  for (int it = 0; it < 64; ++it) {
    float ls = 0.f, lc = 0.f;
#pragma unroll
    for (int j = 0; j < 16; j++) {
      if (s[j] > tau) { ls += s[j]; lc += 1.f; }
    }
    block_reduce2(ls, lc, sm);
    const float ntau = (ls - 1.0f) / lc;
    const int ic = (int)lc;
    const bool conv = (ic == cnt_prev);
    tau = ntau;
    cnt_prev = ic;
    if (conv) break;
  }

  if (fh != nullptr) {
    u16* ph = fh + (size_t)row * 4096;
#pragma unroll
    for (int j = 0; j < 16; j++) {
      const float r = fmaxf(s[j] - tau, 0.f);
      p[t + j * 256] = r;
      ph[t + j * 256] = f2bf(r);
    }
  } else {
#pragma unroll
    for (int j = 0; j < 16; j++) p[t + j * 256] = fmaxf(s[j] - tau, 0.f);
  }
}

// ================================================================ launch
extern "C" void kernel_launch(void* const* d_in, const int* in_sizes, int n_in,
                              void* d_out, int out_size, void* d_ws, size_t ws_size,
                              hipStream_t stream) {
  const float* x    = (const float*)d_in[0];   // [B, N]
  const float* Wq_w = (const float*)d_in[1];   // [A, N]
  const float* Wq_b = (const float*)d_in[2];   // [A]
  const float* Wk   = (const float*)d_in[3];   // [M, A]
  const float* Wv   = (const float*)d_in[4];   // [M, N]
  const float* gq   = (const float*)d_in[5];
  const float* bq   = (const float*)d_in[6];
  const float* gk   = (const float*)d_in[7];
  const float* bk   = (const float*)d_in[8];
  const float* gv   = (const float*)d_in[9];
  const float* bv   = (const float*)d_in[10];

  float* out = (float*)d_out;
  float* out_x    = out;                                  // B*N
  float* out_xhat = out + (size_t)B_DIM * N_DIM;          // B*N
  float* out_f    = out_xhat + (size_t)B_DIM * N_DIM;     // B*M
  float* out_v    = out_f + (size_t)B_DIM * M_DIM;        // M*N

  // ws layout (bf16 planes); x-planes are overwritten by q-planes after qproj.
  u16* wsu = (u16*)d_ws;
  u16* xh = wsu;                                   // [B*N]  (later: qh)
  u16* xl = xh + (size_t)B_DIM * N_DIM;            // [B*N]  (later: ql)
  u16* wqh = xl + (size_t)B_DIM * N_DIM;           // [A*N]
  u16* wql = wqh + (size_t)A_DIM * N_DIM;          // [A*N]
  u16* kh = wql + (size_t)A_DIM * N_DIM;           // [M*A]
  u16* kl = kh + (size_t)M_DIM * A_DIM;            // [M*A]
  u16* vt = kl + (size_t)M_DIM * A_DIM;            // [N*M] bf16 v^T
  u16* fh = vt + (size_t)N_DIM * M_DIM;            // [B*M] bf16 f (optional)
  const size_t need_elems = 2 * (size_t)B_DIM * N_DIM + 2 * (size_t)A_DIM * N_DIM +
                            2 * (size_t)M_DIM * A_DIM + (size_t)N_DIM * M_DIM +
                            (size_t)B_DIM * M_DIM;
  const bool use_fh = ws_size >= need_elems * sizeof(u16);
  // q_pre fp32 borrows the out_xhat region (free until the last GEMM)
  float* q_pre = out_xhat;

  // 1) out_x = x and x -> bf16 hi/lo planes (single read of x)
  copy_split_kernel<<<(B_DIM * N_DIM / 8 + 255) / 256, 256, 0, stream>>>(
      x, out_x, xh, xl, B_DIM * N_DIM / 8);
  // 2) Wq -> bf16 hi/lo planes
  split_convert_kernel<<<(A_DIM * N_DIM / 8 + 255) / 256, 256, 0, stream>>>(
      Wq_w, wqh, wql, A_DIM * N_DIM / 8);
  // 3) k = LN(relu(Wk)) -> bf16 planes ; v = LN(relu(Wv)) -> fp32 out_v
  relu_ln_kernel<<<M_DIM, 256, 0, stream>>>(Wk, nullptr, gk, bk, nullptr, kh, kl);
  relu_ln_kernel<<<M_DIM, 256, 0, stream>>>(Wv, nullptr, gv, bv, out_v, nullptr, nullptr);

  // 4) q_pre = x @ Wq_w^T (split3, bf16 planes)
  gemm_mfma<3, true><<<dim3(A_DIM / 128, B_DIM / 128), 256, 0, stream>>>(
      xh, xl, nullptr, wqh, wql, q_pre, A_DIM, N_DIM, N_DIM, N_DIM);
  // 5) q = LN(relu(q_pre + b)) -> bf16 planes (overwrite x planes)
  relu_ln_kernel<<<B_DIM, 256, 0, stream>>>(q_pre, Wq_b, gq, bq, nullptr, xh, xl);

  // 6) scores = q @ k^T (split3) -> out_f
  gemm_mfma<3, true><<<dim3(M_DIM / 128, B_DIM / 128), 256, 0, stream>>>(
      xh, xl, nullptr, kh, kl, out_f, M_DIM, A_DIM, A_DIM, A_DIM);
  // 7) f = sparsemax(scores / 32) in place (+ bf16 image if ws permits)
  sparsemax_kernel<<<B_DIM, 256, 0, stream>>>(out_f, 0.03125f, use_fh ? fh : nullptr);

  // 8) vT bf16
  transpose_bf16_kernel<<<dim3(N_DIM / 32, M_DIM / 32), 256, 0, stream>>>(out_v, vt);

  // 9) x_hat = f @ vT^T (split1)
  if (use_fh) {
    gemm_mfma<1, true><<<dim3(N_DIM / 128, B_DIM / 128), 256, 0, stream>>>(
        fh, nullptr, nullptr, vt, nullptr, out_xhat, N_DIM, M_DIM, M_DIM, M_DIM);
  } else {
    gemm_mfma<1, false><<<dim3(N_DIM / 128, B_DIM / 128), 256, 0, stream>>>(
        nullptr, nullptr, out_f, vt, nullptr, out_xhat, N_DIM, M_DIM, M_DIM, M_DIM);
  }
}

// Round 5
// 599.096 us; speedup vs baseline: 3.4121x; 1.2245x over previous
//
#include <hip/hip_runtime.h>

// Problem dims (fixed by the reference)
#define B_DIM 8192
#define N_DIM 1024
#define M_DIM 4096
#define A_DIM 1024
#define LN_EPS 1e-5f

typedef short s8v __attribute__((ext_vector_type(8)));   // 8 bf16 (4 VGPRs)
typedef float f4v __attribute__((ext_vector_type(4)));   // 4 fp32 acc
typedef unsigned short u16;

// bf16 round-to-nearest-even, bit-level (inputs finite)
__device__ __forceinline__ u16 f2bf(float f) {
  union { float f; unsigned u; } x; x.f = f;
  unsigned r = x.u + 0x7fffu + ((x.u >> 16) & 1u);
  return (u16)(r >> 16);
}
__device__ __forceinline__ float bf2f(u16 h) {
  union { unsigned u; float f; } x; x.u = ((unsigned)h) << 16;
  return x.f;
}

// async global->LDS, 16 B per lane. LDS dest = wave-uniform base + lane*16.
__device__ __forceinline__ void glds16(const void* g, void* l) {
  __builtin_amdgcn_global_load_lds(
      (const __attribute__((address_space(1))) unsigned int*)g,
      (__attribute__((address_space(3))) unsigned int*)l, 16, 0, 0);
}

// ---------------------------- fused: out_x = x ; xh = bf16(x) (hi plane only)
__global__ __launch_bounds__(256) void copy_cvt_kernel(const float* __restrict__ in,
                                                       float* __restrict__ outc,
                                                       u16* __restrict__ hi, int n8) {
  int i = blockIdx.x * 256 + threadIdx.x;
  if (i >= n8) return;
  const float* src = in + (size_t)i * 8;
  float4 v0 = *(const float4*)src;
  float4 v1 = *(const float4*)(src + 4);
  *(float4*)(outc + (size_t)i * 8) = v0;
  *(float4*)(outc + (size_t)i * 8 + 4) = v1;
  const float f[8] = {v0.x, v0.y, v0.z, v0.w, v1.x, v1.y, v1.z, v1.w};
  s8v h;
#pragma unroll
  for (int j = 0; j < 8; j++) h[j] = (short)f2bf(f[j]);
  *(s8v*)(hi + (size_t)i * 8) = h;
}

// ------------------------------------------------------- fp32 -> bf16 (hi only)
__global__ __launch_bounds__(256) void cvt_kernel(const float* __restrict__ in,
                                                  u16* __restrict__ hi, int n8) {
  int i = blockIdx.x * 256 + threadIdx.x;
  if (i >= n8) return;
  const float* src = in + (size_t)i * 8;
  float4 v0 = *(const float4*)src;
  float4 v1 = *(const float4*)(src + 4);
  const float f[8] = {v0.x, v0.y, v0.z, v0.w, v1.x, v1.y, v1.z, v1.w};
  s8v h;
#pragma unroll
  for (int j = 0; j < 8; j++) h[j] = (short)f2bf(f[j]);
  *(s8v*)(hi + (size_t)i * 8) = h;
}

// ------------------------------------------------- block-wide reduce of 2 floats
__device__ __forceinline__ void block_reduce2(float& a, float& b, float* sm) {
#pragma unroll
  for (int off = 32; off > 0; off >>= 1) {
    a += __shfl_down(a, off, 64);
    b += __shfl_down(b, off, 64);
  }
  const int lane = threadIdx.x & 63;
  const int wid = threadIdx.x >> 6;
  __syncthreads();
  if (lane == 0) { sm[wid * 2] = a; sm[wid * 2 + 1] = b; }
  __syncthreads();
  a = sm[0] + sm[2] + sm[4] + sm[6];
  b = sm[1] + sm[3] + sm[5] + sm[7];
}

// ------------------------- relu(+bias) + LayerNorm, C=1024; fp32 and/or bf16 out
__global__ __launch_bounds__(256) void relu_ln_kernel(const float* __restrict__ in,
                                                      const float* __restrict__ bias,
                                                      const float* __restrict__ g,
                                                      const float* __restrict__ bt,
                                                      float* __restrict__ outf,
                                                      u16* __restrict__ outh,
                                                      u16* __restrict__ outl) {
  __shared__ float sm[8];
  const int row = blockIdx.x;
  const int t = threadIdx.x;
  const float* pin = in + (size_t)row * 1024;

  float4 v = *(const float4*)(pin + t * 4);
  if (bias != nullptr) {
    float4 bb = *(const float4*)(bias + t * 4);
    v.x += bb.x; v.y += bb.y; v.z += bb.z; v.w += bb.w;
  }
  v.x = fmaxf(v.x, 0.f); v.y = fmaxf(v.y, 0.f);
  v.z = fmaxf(v.z, 0.f); v.w = fmaxf(v.w, 0.f);

  float s = v.x + v.y + v.z + v.w;
  float ss = v.x * v.x + v.y * v.y + v.z * v.z + v.w * v.w;
  block_reduce2(s, ss, sm);

  const float mean = s * (1.f / 1024.f);
  const float var = ss * (1.f / 1024.f) - mean * mean;
  const float rs = rsqrtf(var + LN_EPS);

  const float4 gg = *(const float4*)(g + t * 4);
  const float4 bb = *(const float4*)(bt + t * 4);
  float o[4];
  o[0] = (v.x - mean) * rs * gg.x + bb.x;
  o[1] = (v.y - mean) * rs * gg.y + bb.y;
  o[2] = (v.z - mean) * rs * gg.z + bb.z;
  o[3] = (v.w - mean) * rs * gg.w + bb.w;

  if (outf != nullptr)
    *(float4*)(outf + (size_t)row * 1024 + t * 4) = make_float4(o[0], o[1], o[2], o[3]);
  if (outh != nullptr) {
    ushort4 h, l;
    h.x = f2bf(o[0]); h.y = f2bf(o[1]); h.z = f2bf(o[2]); h.w = f2bf(o[3]);
    l.x = f2bf(o[0] - bf2f(h.x)); l.y = f2bf(o[1] - bf2f(h.y));
    l.z = f2bf(o[2] - bf2f(h.z)); l.w = f2bf(o[3] - bf2f(h.w));
    *(ushort4*)(outh + (size_t)row * 1024 + t * 4) = h;
    *(ushort4*)(outl + (size_t)row * 1024 + t * 4) = l;
  }
}

// ------------------------------------------------- split-bf16 MFMA GEMM (nt)
// C[M_,N_] = A[M_,K] * B[N_,K]^T; A,B pre-split bf16 planes staged via glds.
// 128x128 tile, BK=32, 4 waves, each 64x64 via 4x4 of mfma 16x16x32 bf16.
// LDS rows: 32 bf16 = 4 chunks of 16 B; chunk c at slot c^((row>>1)&3)
// (2-way bank aliasing on ds_read_b128 = free; glds-compatible).
template <int NSPLIT>
__global__ __launch_bounds__(256) void gemm_mfma(const u16* __restrict__ AhG,
                                                 const u16* __restrict__ AlG,
                                                 const u16* __restrict__ BhG,
                                                 const u16* __restrict__ BlG,
                                                 float* __restrict__ C,
                                                 int N_, int K, int lda, int ldb) {
  __shared__ __align__(16) u16 Ah[128 * 32];
  __shared__ __align__(16) u16 Bh[128 * 32];
  __shared__ __align__(16) u16 Al[NSPLIT == 3 ? 128 * 32 : 8];
  __shared__ __align__(16) u16 Bl[NSPLIT == 3 ? 128 * 32 : 8];

  const int t = threadIdx.x;
  const int lane = t & 63;
  const int wv = t >> 6;
  const int wm = (wv & 1) * 64;
  const int wn = (wv >> 1) * 64;
  const int m0 = blockIdx.y * 128;
  const int n0 = blockIdx.x * 128;

  // glds lane geometry: within a 16-row chunk, lane covers row=lane>>2, slot=lane&3
  const int ge = lane >> 2;
  const int gg = (lane & 3) ^ ((ge >> 1) & 3);  // global k-chunk to fetch

  // fragment geometry: lane reads row (lane&15), logical chunk (lane>>4)
  const int fr = lane & 15;
  const int fslot = (((lane >> 4) ^ ((fr >> 1) & 3))) * 8;

  f4v acc[4][4];
#pragma unroll
  for (int i = 0; i < 4; i++)
#pragma unroll
    for (int j = 0; j < 4; j++) acc[i][j] = (f4v)(0.f);

  for (int k0 = 0; k0 < K; k0 += 32) {
#pragma unroll
    for (int h = 0; h < 2; h++) {
      const int c = wv * 2 + h;               // chunk 0..7
      const size_t aoff = (size_t)(m0 + c * 16 + ge) * lda + k0 + gg * 8;
      const size_t boff = (size_t)(n0 + c * 16 + ge) * ldb + k0 + gg * 8;
      glds16(AhG + aoff, &Ah[c * 512]);
      glds16(BhG + boff, &Bh[c * 512]);
      if constexpr (NSPLIT == 3) {
        glds16(AlG + aoff, &Al[c * 512]);
        glds16(BlG + boff, &Bl[c * 512]);
      }
    }
    __syncthreads();

    s8v ah[4], bh[4], al[4], bl[4];
#pragma unroll
    for (int i = 0; i < 4; i++) {
      ah[i] = *(const s8v*)&Ah[(wm + i * 16 + fr) * 32 + fslot];
      bh[i] = *(const s8v*)&Bh[(wn + i * 16 + fr) * 32 + fslot];
      if constexpr (NSPLIT == 3) {
        al[i] = *(const s8v*)&Al[(wm + i * 16 + fr) * 32 + fslot];
        bl[i] = *(const s8v*)&Bl[(wn + i * 16 + fr) * 32 + fslot];
      }
    }
#pragma unroll
    for (int i = 0; i < 4; i++)
#pragma unroll
      for (int j = 0; j < 4; j++) {
        acc[i][j] = __builtin_amdgcn_mfma_f32_16x16x32_bf16(ah[i], bh[j], acc[i][j], 0, 0, 0);
        if constexpr (NSPLIT == 3) {
          acc[i][j] = __builtin_amdgcn_mfma_f32_16x16x32_bf16(ah[i], bl[j], acc[i][j], 0, 0, 0);
          acc[i][j] = __builtin_amdgcn_mfma_f32_16x16x32_bf16(al[i], bh[j], acc[i][j], 0, 0, 0);
        }
      }
    __syncthreads();
  }

  // epilogue: C/D layout 16x16x32: col = lane&15, row = (lane>>4)*4 + reg
  const int cr = (lane >> 4) * 4;
  const int cc = lane & 15;
#pragma unroll
  for (int i = 0; i < 4; i++)
#pragma unroll
    for (int r = 0; r < 4; r++) {
      float* cp = C + (size_t)(m0 + wm + i * 16 + cr + r) * N_ + n0 + wn + cc;
#pragma unroll
      for (int j = 0; j < 4; j++) cp[j * 16] = acc[i][j][r];
    }
}

// --------------------------------------- fused sparsemax + sparse x_hat = f @ v
// Michelot simplex projection (exact sparsemax tau; fixed point of
// tau <- (sum_{s>tau} s - 1)/|{s>tau}|, identical to the sort/cumsum ref).
// Then compacts the active set (typically ~5-30 of 4096) to LDS and gathers
// only those v rows for x_hat — replaces the dense 68.7 GF x_hat GEMM.
__global__ __launch_bounds__(256) void sparsemax_xhat_kernel(
    float* __restrict__ sf,        // [B,4096] in: raw scores, out: f
    const float* __restrict__ v,   // [4096,1024] fp32
    float* __restrict__ xhat,      // [B,1024]
    float scale) {
  __shared__ float sm[8];
  __shared__ int s_idx[4096];
  __shared__ float s_w[4096];
  __shared__ int s_cnt;
  const int row = blockIdx.x;
  float* p = sf + (size_t)row * 4096;
  const int t = threadIdx.x;
  const int lane = t & 63;

  float s[16];
#pragma unroll
  for (int j = 0; j < 16; j++) {
    float vv = p[t + j * 256] * scale;
    s[j] = (vv < -1e10f) ? 0.f : vv;   // faithful to the reference mask
  }

  float tau = -INFINITY;
  int cnt_prev = -1;
  for (int it = 0; it < 64; ++it) {
    float ls = 0.f, lc = 0.f;
#pragma unroll
    for (int j = 0; j < 16; j++) {
      if (s[j] > tau) { ls += s[j]; lc += 1.f; }
    }
    block_reduce2(ls, lc, sm);          // broadcast: uniform across block
    const float ntau = (ls - 1.0f) / lc;
    const int ic = (int)lc;
    const bool conv = (ic == cnt_prev);
    tau = ntau;
    cnt_prev = ic;
    if (conv) break;                    // uniform condition
  }

  if (t == 0) s_cnt = 0;
  __syncthreads();

  // write f and compact active (index, weight) pairs into LDS
#pragma unroll
  for (int j = 0; j < 16; j++) {
    const float fv = fmaxf(s[j] - tau, 0.f);
    p[t + j * 256] = fv;
    const bool pred = fv > 0.f;
    const unsigned long long m = __ballot(pred);
    if (m) {
      int base = 0;
      if (lane == 0) base = atomicAdd(&s_cnt, (int)__popcll(m));
      base = __shfl(base, 0, 64);
      if (pred) {
        const int pos = base + (int)__popcll(m & ((1ull << lane) - 1ull));
        s_idx[pos] = t + j * 256;
        s_w[pos] = fv;
      }
    }
  }
  __syncthreads();

  const int cnt = s_cnt;
  float4 acc = make_float4(0.f, 0.f, 0.f, 0.f);
  int e = 0;
  for (; e + 4 <= cnt; e += 4) {
    const int m0 = s_idx[e], m1 = s_idx[e + 1], m2 = s_idx[e + 2], m3 = s_idx[e + 3];
    const float w0 = s_w[e], w1 = s_w[e + 1], w2 = s_w[e + 2], w3 = s_w[e + 3];
    const float4 v0 = *(const float4*)(v + (size_t)m0 * 1024 + t * 4);
    const float4 v1 = *(const float4*)(v + (size_t)m1 * 1024 + t * 4);
    const float4 v2 = *(const float4*)(v + (size_t)m2 * 1024 + t * 4);
    const float4 v3 = *(const float4*)(v + (size_t)m3 * 1024 + t * 4);
    acc.x += w0 * v0.x + w1 * v1.x + w2 * v2.x + w3 * v3.x;
    acc.y += w0 * v0.y + w1 * v1.y + w2 * v2.y + w3 * v3.y;
    acc.z += w0 * v0.z + w1 * v1.z + w2 * v2.z + w3 * v3.z;
    acc.w += w0 * v0.w + w1 * v1.w + w2 * v2.w + w3 * v3.w;
  }
  for (; e < cnt; e++) {
    const int m0 = s_idx[e];
    const float w0 = s_w[e];
    const float4 v0 = *(const float4*)(v + (size_t)m0 * 1024 + t * 4);
    acc.x += w0 * v0.x; acc.y += w0 * v0.y;
    acc.z += w0 * v0.z; acc.w += w0 * v0.w;
  }
  *(float4*)(xhat + (size_t)row * 1024 + t * 4) = acc;
}

// ================================================================ launch
extern "C" void kernel_launch(void* const* d_in, const int* in_sizes, int n_in,
                              void* d_out, int out_size, void* d_ws, size_t ws_size,
                              hipStream_t stream) {
  const float* x    = (const float*)d_in[0];   // [B, N]
  const float* Wq_w = (const float*)d_in[1];   // [A, N]
  const float* Wq_b = (const float*)d_in[2];   // [A]
  const float* Wk   = (const float*)d_in[3];   // [M, A]
  const float* Wv   = (const float*)d_in[4];   // [M, N]
  const float* gq   = (const float*)d_in[5];
  const float* bq   = (const float*)d_in[6];
  const float* gk   = (const float*)d_in[7];
  const float* bk   = (const float*)d_in[8];
  const float* gv   = (const float*)d_in[9];
  const float* bv   = (const float*)d_in[10];

  float* out = (float*)d_out;
  float* out_x    = out;                                  // B*N
  float* out_xhat = out + (size_t)B_DIM * N_DIM;          // B*N
  float* out_f    = out_xhat + (size_t)B_DIM * N_DIM;     // B*M
  float* out_v    = out_f + (size_t)B_DIM * M_DIM;        // M*N

  // ws layout (bf16 planes), 27.3M elems = 54.6 MB total:
  // slot0 [8.4M]: xh (input to qproj), later overwritten by ql
  // slot1 [8.4M]: qh ; then wqh [2.1M], kh [4.2M], kl [4.2M]
  u16* wsu = (u16*)d_ws;
  u16* xh_ql = wsu;                                  // [B*N] xh -> ql
  u16* qh  = xh_ql + (size_t)B_DIM * N_DIM;          // [B*A]
  u16* wqh = qh + (size_t)B_DIM * A_DIM;             // [A*N]
  u16* kh  = wqh + (size_t)A_DIM * N_DIM;            // [M*A]
  u16* kl  = kh + (size_t)M_DIM * A_DIM;             // [M*A]
  // q_pre fp32 borrows out_xhat (dead until sparsemax_xhat writes it)
  float* q_pre = out_xhat;

  // 1) out_x = x ; xh = bf16(x)
  copy_cvt_kernel<<<(B_DIM * N_DIM / 8 + 255) / 256, 256, 0, stream>>>(
      x, out_x, xh_ql, B_DIM * N_DIM / 8);
  // 2) wqh = bf16(Wq_w)
  cvt_kernel<<<(A_DIM * N_DIM / 8 + 255) / 256, 256, 0, stream>>>(
      Wq_w, wqh, A_DIM * N_DIM / 8);
  // 3) k = LN(relu(Wk)) -> bf16 hi/lo ; v = LN(relu(Wv)) -> fp32 out_v
  relu_ln_kernel<<<M_DIM, 256, 0, stream>>>(Wk, nullptr, gk, bk, nullptr, kh, kl);
  relu_ln_kernel<<<M_DIM, 256, 0, stream>>>(Wv, nullptr, gv, bv, out_v, nullptr, nullptr);

  // 4) q_pre = x @ Wq_w^T (split1: feeds LN, bf16 error washes out)
  gemm_mfma<1><<<dim3(A_DIM / 128, B_DIM / 128), 256, 0, stream>>>(
      xh_ql, nullptr, wqh, nullptr, q_pre, A_DIM, N_DIM, N_DIM, N_DIM);
  // 5) q = LN(relu(q_pre + b)) -> qh/ql (ql overwrites dead xh)
  relu_ln_kernel<<<B_DIM, 256, 0, stream>>>(q_pre, Wq_b, gq, bq, nullptr, qh, xh_ql);

  // 6) scores = q @ k^T (split3: hh+hl+lh, ~fp32 accuracy) -> out_f
  gemm_mfma<3><<<dim3(M_DIM / 128, B_DIM / 128), 256, 0, stream>>>(
      qh, xh_ql, kh, kl, out_f, M_DIM, A_DIM, A_DIM, A_DIM);

  // 7) f = sparsemax(scores/32) in place + x_hat = f @ v (sparse gather, fp32)
  sparsemax_xhat_kernel<<<B_DIM, 256, 0, stream>>>(out_f, out_v, out_xhat, 0.03125f);
}